// Round 7
// baseline (465860.596 us; speedup 1.0000x reference)
//
#include <hip/hip_runtime.h>
#include <math.h>
#include <utility>

#define ND 64
#define PAD 65
#define NN 4096
#define NB 8192

// ws layout (floats)
#define OFF_MEANPART ((size_t)0)        // 32*4096
#define OFF_MEANA    ((size_t)131072)
#define OFF_S        ((size_t)135168)
#define OFF_SI       ((size_t)139264)
#define OFF_SS       ((size_t)143360)
#define OFF_TBAR     ((size_t)147456)
#define OFF_MI       ((size_t)151552)
#define OFF_P        ((size_t)155648)
#define OFF_VARPART  ((size_t)155712)   // 2048 slots
#define OFF_LAM      ((size_t)157760)   // NB*ND = 524288
#define OFF_TPART    ((size_t)682048)   // G2*4096 per-block partials

#define G2_BLOCKS 2048
#define G3_BLOCKS 2048

typedef int v2i __attribute__((ext_vector_type(2)));

// ---------------------------------------------------------------------------
// lane-exchange primitives (all bit-exact)
// ---------------------------------------------------------------------------
template<int CTRL>
__device__ __forceinline__ float dppf(float x) {
  return __builtin_bit_cast(float,
      __builtin_amdgcn_mov_dpp(__builtin_bit_cast(int, x), CTRL, 0xF, 0xF, true));
}
__device__ __forceinline__ float bperm_f(int pa, float x) {
  return __builtin_bit_cast(float,
      __builtin_amdgcn_ds_bpermute(pa, __builtin_bit_cast(int, x)));
}
// lane^16 / lane^32 via permlane*_swap; swap(x,x) gives per-lane the multiset
// {x[lane], x[lane^K]}; A+B-x in integer arithmetic reconstructs x[lane^K]
// exactly regardless of output-order convention. (pl16x HW-validated in the
// passing round-2/3 kernels; pl32x same construction, T12/m255 semantics.)
__device__ __forceinline__ float pl16x(float x) {
  int xi = __builtin_bit_cast(int, x);
  v2i pr = __builtin_amdgcn_permlane16_swap(xi, xi, false, false);
  unsigned r = (unsigned)pr.x + (unsigned)pr.y - (unsigned)xi;
  return __builtin_bit_cast(float, (int)r);
}
__device__ __forceinline__ float pl32x(float x) {
  int xi = __builtin_bit_cast(int, x);
  v2i pr = __builtin_amdgcn_permlane32_swap(xi, xi, false, false);
  unsigned r = (unsigned)pr.x + (unsigned)pr.y - (unsigned)xi;
  return __builtin_bit_cast(float, (int)r);
}

// XOR-distance exchange on the VALU: quad_perm for ^1/^2/^3,
// row_half_mirror=^7, row_mirror=^15, composites for the rest of the low
// nibble (<=3 ops), permlane16/32_swap for bits 16/32.
template<int R>
__device__ __forceinline__ float xorlane(float x) {
  constexpr int lo = R & 15;
  float t = x;
  if constexpr (lo == 1)       t = dppf<0xB1>(t);
  else if constexpr (lo == 2)  t = dppf<0x4E>(t);
  else if constexpr (lo == 3)  t = dppf<0x1B>(t);
  else if constexpr (lo == 4)  { t = dppf<0x141>(t); t = dppf<0x1B>(t); }
  else if constexpr (lo == 5)  { t = dppf<0x141>(t); t = dppf<0x4E>(t); }
  else if constexpr (lo == 6)  { t = dppf<0x141>(t); t = dppf<0xB1>(t); }
  else if constexpr (lo == 7)  t = dppf<0x141>(t);
  else if constexpr (lo == 8)  { t = dppf<0x140>(t); t = dppf<0x141>(t); }
  else if constexpr (lo == 9)  { t = dppf<0x140>(t); t = dppf<0x141>(t); t = dppf<0xB1>(t); }
  else if constexpr (lo == 10) { t = dppf<0x140>(t); t = dppf<0x141>(t); t = dppf<0x4E>(t); }
  else if constexpr (lo == 11) { t = dppf<0x140>(t); t = dppf<0x141>(t); t = dppf<0x1B>(t); }
  else if constexpr (lo == 12) { t = dppf<0x140>(t); t = dppf<0x1B>(t); }
  else if constexpr (lo == 13) { t = dppf<0x140>(t); t = dppf<0x4E>(t); }
  else if constexpr (lo == 14) { t = dppf<0x140>(t); t = dppf<0xB1>(t); }
  else if constexpr (lo == 15) t = dppf<0x140>(t);
  if constexpr (R & 16) t = pl16x(t);
  if constexpr (R & 32) t = pl32x(t);
  return t;
}

constexpr int xlocost(int lo) {
  constexpr int t[16] = {0,1,1,1,2,2,2,1,2,3,3,3,2,2,2,1};
  return t[lo];
}
constexpr int xcost(int R) { return xlocost(R & 15) + ((R >> 4) & 1) + ((R >> 5) & 1); }

// ---------------------------------------------------------------------------
// XOR-swizzled 64x64 LDS tile addressing (float indices).
// ---------------------------------------------------------------------------
__device__ __forceinline__ constexpr int skey(int row) { return (row + (row >> 4)) & 15; }
__device__ __forceinline__ int swz4(int row, int g) { return row * 64 + ((g ^ skey(row)) << 2); }
__device__ __forceinline__ int swzE(int row, int e) {
  return row * 64 + (((e >> 2) ^ skey(row)) << 2) + (e & 3);
}

// ---------------------------------------------------------------------------
// Team Jacobi round (2 waves per matrix; wave wv holds rows [32wv,32wv+32) of
// every column; lane = column). Cross-wave apq via ping-pong LDS share.
// parity alternates between consecutive rounds INCLUDING across sweep
// boundaries. Exactly one barrier per round regardless of rotation decisions
// -> no divergent-barrier hazard even under FP divergence.
// ---------------------------------------------------------------------------
template<int R>
__device__ __forceinline__ bool round_step(float (&w)[32], float &g, float* shr,
                                           int parity, int lane, int wv) {
  float v[32]; float gv;
  if constexpr (xcost(R) >= 4) {
    int pa = (lane ^ R) << 2;
#pragma unroll
    for (int i = 0; i < 32; ++i) {
      float t = bperm_f(pa, w[i]);
      asm volatile("" : "+v"(t));
      v[i] = t;
    }
    { float t = bperm_f(pa, g); asm volatile("" : "+v"(t)); gv = t; }
  } else {
#pragma unroll
    for (int i = 0; i < 32; ++i) v[i] = xorlane<R>(w[i]);
    gv = xorlane<R>(g);
  }
  float a0 = 0.f, a1 = 0.f, a2 = 0.f, a3 = 0.f;
#pragma unroll
  for (int i = 0; i < 32; i += 4) {
    a0 = fmaf(w[i + 0], v[i + 0], a0);
    a1 = fmaf(w[i + 1], v[i + 1], a1);
    a2 = fmaf(w[i + 2], v[i + 2], a2);
    a3 = fmaf(w[i + 3], v[i + 3], a3);
  }
  float pd = (a0 + a1) + (a2 + a3);
  shr[(parity * 2 + wv) * 64 + lane] = pd;
  __syncthreads();
  float apq = shr[(parity * 2 + 0) * 64 + lane] + shr[(parity * 2 + 1) * 64 + lane];
  bool rot = (apq * apq > 4e-10f * g * gv);
  if (rot) {
    int partner = lane ^ R;
    bool amP = lane < partner;
    float app = amP ? g : gv;
    float aqq = amP ? gv : g;
    float tau = (aqq - app) / (2.f * apq);
    float t = 1.f / (fabsf(tau) + sqrtf(1.f + tau * tau));
    t = (tau < 0.f) ? -t : t;
    float cr = 1.f / sqrtf(1.f + t * t);
    float sr = t * cr;
    float s2v = amP ? -sr : sr;
#pragma unroll
    for (int i = 0; i < 32; ++i) w[i] = fmaf(s2v, v[i], cr * w[i]);
    float d = t * apq;
    g = amP ? (g - d) : (g + d);
  }
  return __any(rot);
}

template<int... Is>
__device__ __forceinline__ bool sweep_impl(float (&w)[32], float &g, float* shr,
                                           int lane, int wv, int sweep,
                                           std::integer_sequence<int, Is...>) {
  bool any = false;
  // 63 rounds/sweep (odd) -> (sweep + Is) & 1 alternates continuously across
  // sweep boundaries as well as within a sweep.
  ((any = round_step<Is + 1>(w, g, shr, (sweep + Is) & 1, lane, wv) || any), ...);
  return any;
}

// shr slots: 0/1 round ping-pong, 2 init, 3 post (512 floats).
// anyf: 2-int shared flag for BLOCK-UNIFORM sweep termination.
__device__ __forceinline__ float jacobi_team(float (&w)[32], float* shr, int* anyf,
                                             int lane, int wv) {
  float a0 = 0.f, a1 = 0.f, a2 = 0.f, a3 = 0.f;
#pragma unroll
  for (int i = 0; i < 32; i += 4) {
    a0 = fmaf(w[i + 0], w[i + 0], a0);
    a1 = fmaf(w[i + 1], w[i + 1], a1);
    a2 = fmaf(w[i + 2], w[i + 2], a2);
    a3 = fmaf(w[i + 3], w[i + 3], a3);
  }
  float pd = (a0 + a1) + (a2 + a3);
  shr[(2 * 2 + wv) * 64 + lane] = pd;
  __syncthreads();
  float g = shr[(2 * 2 + 0) * 64 + lane] + shr[(2 * 2 + 1) * 64 + lane];
  for (int sweep = 0; sweep < 18; ++sweep) {
    bool any = sweep_impl(w, g, shr, lane, wv, sweep,
                          std::make_integer_sequence<int, 63>{});
    anyf[wv] = any ? 1 : 0;
    __syncthreads();               // also fences last round's shr reads
    int combined = anyf[0] | anyf[1];
    if (!combined) break;          // uniform across both waves by construction
  }
  a0 = a1 = a2 = a3 = 0.f;
#pragma unroll
  for (int i = 0; i < 32; i += 4) {
    a0 = fmaf(w[i + 0], w[i + 0], a0);
    a1 = fmaf(w[i + 1], w[i + 1], a1);
    a2 = fmaf(w[i + 2], w[i + 2], a2);
    a3 = fmaf(w[i + 3], w[i + 3], a3);
  }
  pd = (a0 + a1) + (a2 + a3);
  shr[(3 * 2 + wv) * 64 + lane] = pd;
  __syncthreads();
  return shr[(3 * 2 + 0) * 64 + lane] + shr[(3 * 2 + 1) * 64 + lane];
}

// ---------------------------------------------------------------------------
// Team congruence: M = q*(x*q) for symmetric q; wave wv ends with its half
// rows of M's column `lane` in w[32]. Xb = 4096-float swizzled tile.
// ---------------------------------------------------------------------------
__device__ __forceinline__ void congruence_team(const float* __restrict__ xi,
                                                const float* __restrict__ q,
                                                float* __restrict__ Xb,
                                                int lane, int wv,
                                                float (&w)[32]) {
#pragma unroll
  for (int k = 0; k < 8; ++k) {
    int flat = wv * 2048 + k * 256 + lane * 4;
    float4 rv = *(const float4*)(xi + flat);
    int a = flat >> 6;
    *(float4*)(Xb + swz4(a, lane & 15)) = rv;
  }
  __syncthreads();
  // step1: B[r] = sum_a x[a][32wv+r] * q[a][lane]   (x, q symmetric)
  float B[32];
#pragma unroll
  for (int r = 0; r < 32; ++r) B[r] = 0.f;
  const float* qc = q + lane * 64;
  for (int a4 = 0; a4 < 64; a4 += 4) {
    float4 s4 = *(const float4*)(qc + a4);
#pragma unroll
    for (int t = 0; t < 4; ++t) {
      int a = a4 + t;
      float sa = (t == 0) ? s4.x : (t == 1) ? s4.y : (t == 2) ? s4.z : s4.w;
#pragma unroll
      for (int g2 = 0; g2 < 8; ++g2) {
        float4 xa = *(const float4*)(Xb + swz4(a, 8 * wv + g2));
        B[4 * g2 + 0] = fmaf(xa.x, sa, B[4 * g2 + 0]);
        B[4 * g2 + 1] = fmaf(xa.y, sa, B[4 * g2 + 1]);
        B[4 * g2 + 2] = fmaf(xa.z, sa, B[4 * g2 + 2]);
        B[4 * g2 + 3] = fmaf(xa.w, sa, B[4 * g2 + 3]);
      }
    }
  }
  __syncthreads();
  // park B as T[c][e] = B[e][c]
#pragma unroll
  for (int g2 = 0; g2 < 8; ++g2) {
    float4 b4 = make_float4(B[4 * g2 + 0], B[4 * g2 + 1], B[4 * g2 + 2], B[4 * g2 + 3]);
    *(float4*)(Xb + swz4(lane, 8 * wv + g2)) = b4;
  }
  __syncthreads();
  // step2: w[r] = sum_a q[32wv+r][a] * B[a][lane]
#pragma unroll
  for (int r = 0; r < 32; ++r) w[r] = 0.f;
  for (int a = 0; a < 64; ++a) {
    float ba = Xb[swzE(lane, a)];
    const float* qr = q + a * 64 + 32 * wv;
#pragma unroll
    for (int r = 0; r < 32; ++r) w[r] = fmaf(qr[r], ba, w[r]);
  }
}

// ---------------------------------------------------------------------------
// Two-sided LDS Jacobi (256 threads, one 64x64 matrix) for the few singles.
// ---------------------------------------------------------------------------
__device__ void jacobi2s(float (&A)[ND][PAD], float (&V)[ND][PAD], int tid) {
  __shared__ float cs_[32], sn_[32];
  __shared__ int   pp_[32], qq_[32];
  __shared__ int   rotcnt_;
  __shared__ float fro2_;
  __shared__ float red_[4];

  __syncthreads();
  float loc = 0.f;
  for (int e = tid; e < NN; e += 256) { float a = A[e >> 6][e & 63]; loc += a * a; }
  for (int o = 32; o; o >>= 1) loc += __shfl_down(loc, o);
  if ((tid & 63) == 0) red_[tid >> 6] = loc;
  __syncthreads();
  if (tid == 0) fro2_ = red_[0] + red_[1] + red_[2] + red_[3];
  __syncthreads();
  float fro2 = fro2_;

  for (int sweep = 0; sweep < 20; ++sweep) {
    if (tid == 0) rotcnt_ = 0;
    __syncthreads();
    for (int r = 0; r < 63; ++r) {
      if (tid < 32) {
        int p, q;
        if (tid == 0) { p = 63; q = r; }
        else { p = (r + tid) % 63; q = (r + 63 - tid) % 63; }
        if (p > q) { int t0 = p; p = q; q = t0; }
        pp_[tid] = p; qq_[tid] = q;
        float app = A[p][p], aqq = A[q][q], apq = A[p][q];
        float thr = fmaxf(1e-12f * fabsf(app * aqq), 1e-14f * fro2);
        float c = 1.f, s = 0.f;
        if (apq * apq > thr) {
          float tau = (aqq - app) / (2.f * apq);
          float t = 1.f / (fabsf(tau) + sqrtf(1.f + tau * tau));
          t = (tau < 0.f) ? -t : t;
          c = 1.f / sqrtf(1.f + t * t);
          s = t * c;
          atomicAdd(&rotcnt_, 1);
        }
        cs_[tid] = c; sn_[tid] = s;
      }
      __syncthreads();
      for (int t = tid; t < 2048; t += 256) {
        int k = t >> 6, j = t & 63;
        int p = pp_[k], q = qq_[k]; float c = cs_[k], s = sn_[k];
        float ap = A[p][j], aq = A[q][j];
        A[p][j] = c * ap - s * aq;
        A[q][j] = s * ap + c * aq;
      }
      __syncthreads();
      for (int t = tid; t < 4096; t += 256) {
        int k = (t >> 6) & 31, j = t & 63;
        int p = pp_[k], q = qq_[k]; float c = cs_[k], s = sn_[k];
        if (t < 2048) {
          float ap = A[j][p], aq = A[j][q];
          A[j][p] = c * ap - s * aq;
          A[j][q] = s * ap + c * aq;
        } else {
          float vp = V[j][p], vq = V[j][q];
          V[j][p] = c * vp - s * vq;
          V[j][q] = s * vp + c * vq;
        }
      }
      __syncthreads();
    }
    int rc = rotcnt_;
    __syncthreads();
    if (rc == 0) break;
  }
}

__device__ void recon_write(const float (&V)[ND][PAD], const float* f, float* g,
                            int c, int wq) {
  float acc[16];
#pragma unroll
  for (int k = 0; k < 16; ++k) acc[k] = 0.f;
  for (int j = 0; j < ND; ++j) {
    float m = f[j] * V[c][j];
#pragma unroll
    for (int k = 0; k < 16; ++k) acc[k] = fmaf(V[wq + 4 * k][j], m, acc[k]);
  }
#pragma unroll
  for (int k = 0; k < 16; ++k) g[(wq + 4 * k) * ND + c] = acc[k];
}

// ---------------------------------------------------------------------------
// Kernels
// ---------------------------------------------------------------------------
__global__ __launch_bounds__(256) void k_mean_part(const float* __restrict__ x,
                                                   float* __restrict__ part) {
  int e = blockIdx.x * 256 + threadIdx.x;
  int chunk = blockIdx.y;
  const float* px = x + (size_t)chunk * 256 * NN + e;
  float s = 0.f;
  for (int i = 0; i < 256; ++i) s += px[(size_t)i * NN];
  part[(size_t)chunk * NN + e] = s;
}

__global__ __launch_bounds__(256) void k_mean_final(const float* __restrict__ part,
                                                    float* __restrict__ meanA) {
  int e = blockIdx.x * 256 + threadIdx.x;
  float s = 0.f;
  for (int c = 0; c < 32; ++c) s += part[(size_t)c * NN + e];
  meanA[e] = s * (1.f / (float)NB);
}

__global__ __launch_bounds__(256) void k_prep1(const float* __restrict__ meanA,
                                               const float* __restrict__ shift,
                                               float* __restrict__ s_out,
                                               float* __restrict__ si_out,
                                               float* __restrict__ ss_out) {
  __shared__ float A[ND][PAD], V[ND][PAD];
  __shared__ float f1[ND], f2[ND];
  int tid = threadIdx.x;
  const float* src = (blockIdx.x == 0) ? meanA : shift;
  for (int e = tid; e < NN; e += 256) A[e >> 6][e & 63] = src[e];
  for (int e = tid; e < NN; e += 256) V[e >> 6][e & 63] = ((e >> 6) == (e & 63)) ? 1.f : 0.f;
  jacobi2s(A, V, tid);
  if (tid < ND) {
    float wv = fmaxf(A[tid][tid], 1e-30f);
    f1[tid] = sqrtf(wv);
    f2[tid] = 1.f / sqrtf(wv);
  }
  __syncthreads();
  int c = tid & 63, wq = tid >> 6;
  if (blockIdx.x == 0) {
    recon_write(V, f1, s_out, c, wq);
    recon_write(V, f2, si_out, c, wq);
  } else {
    recon_write(V, f1, ss_out, c, wq);
  }
}

// batched Karcher tangent accumulation: 2 waves per matrix
__global__ __launch_bounds__(128, 4) void k_stage2(const float* __restrict__ x,
                                                   const float* __restrict__ si,
                                                   float* __restrict__ tPart,
                                                   int G2) {
  __shared__ float Xb[4096];
  __shared__ float shr[512];
  __shared__ float lw[64];
  __shared__ int   anyf[2];
  int tid = threadIdx.x, lane = tid & 63, wv = tid >> 6;

  float tacc[32];
#pragma unroll
  for (int i = 0; i < 32; ++i) tacc[i] = 0.f;

  for (int i = blockIdx.x; i < NB; i += G2) {
    __syncthreads();
    float w[32];
    congruence_team(x + (size_t)i * NN, si, Xb, lane, wv, w);
    float s2 = jacobi_team(w, shr, anyf, lane, wv);
    float sig = sqrtf(fmaxf(s2, 1e-38f));
    float inv = 1.f / sig;
    if (wv == 0) lw[lane] = logf(sig);
    // park U as T[c][e] = U[e][c]  (row c of Xb = eigenvector u_c)
#pragma unroll
    for (int g2 = 0; g2 < 8; ++g2) {
      float4 u4 = make_float4(w[4 * g2 + 0] * inv, w[4 * g2 + 1] * inv,
                              w[4 * g2 + 2] * inv, w[4 * g2 + 3] * inv);
      *(float4*)(Xb + swz4(lane, 8 * wv + g2)) = u4;
    }
    __syncthreads();
    // t[r][lane] += lw[j] * (u_j)_lane * (u_j)_r
    for (int j = 0; j < 64; ++j) {
      float ucj = Xb[swzE(j, lane)];
      float m = lw[j] * ucj;
#pragma unroll
      for (int g2 = 0; g2 < 8; ++g2) {
        float4 u4 = *(const float4*)(Xb + swz4(j, 8 * wv + g2));
        tacc[4 * g2 + 0] = fmaf(u4.x, m, tacc[4 * g2 + 0]);
        tacc[4 * g2 + 1] = fmaf(u4.y, m, tacc[4 * g2 + 1]);
        tacc[4 * g2 + 2] = fmaf(u4.z, m, tacc[4 * g2 + 2]);
        tacc[4 * g2 + 3] = fmaf(u4.w, m, tacc[4 * g2 + 3]);
      }
    }
  }
#pragma unroll
  for (int r = 0; r < 32; ++r)
    tPart[(size_t)blockIdx.x * NN + (32 * wv + r) * 64 + lane] = tacc[r];
}

__global__ __launch_bounds__(256) void k_reduce_t(const float* __restrict__ tPart,
                                                  float* __restrict__ tbar, int nw) {
  int e = blockIdx.x * 256 + threadIdx.x;
  float s = 0.f;
  for (int b = 0; b < nw; ++b) s += tPart[(size_t)b * NN + e];
  tbar[e] = s * (1.f / (float)NB);
}

__global__ __launch_bounds__(256) void k_prep2(const float* __restrict__ tbar,
                                               const float* __restrict__ s_g,
                                               float* __restrict__ mi_out) {
  __shared__ float A[ND][PAD], V[ND][PAD];
  __shared__ float f1[ND];
  int tid = threadIdx.x;
  int c = tid & 63, wq = tid >> 6;
  for (int e = tid; e < NN; e += 256) A[e >> 6][e & 63] = tbar[e];
  for (int e = tid; e < NN; e += 256) V[e >> 6][e & 63] = ((e >> 6) == (e & 63)) ? 1.f : 0.f;
  jacobi2s(A, V, tid);
  if (tid < ND) f1[tid] = expf(A[tid][tid]);
  __syncthreads();
  {
    float acc[16];
#pragma unroll
    for (int k = 0; k < 16; ++k) acc[k] = 0.f;
    for (int j = 0; j < ND; ++j) {
      float m = f1[j] * V[c][j];
#pragma unroll
      for (int k = 0; k < 16; ++k) acc[k] = fmaf(V[wq + 4 * k][j], m, acc[k]);
    }
    __syncthreads();
#pragma unroll
    for (int k = 0; k < 16; ++k) A[wq + 4 * k][c] = acc[k];
  }
  __syncthreads();
  {
    float acc[16];
#pragma unroll
    for (int k = 0; k < 16; ++k) acc[k] = 0.f;
    for (int a = 0; a < ND; ++a) {
      float ea = A[a][c];
#pragma unroll
      for (int k = 0; k < 16; ++k) acc[k] = fmaf(s_g[(wq + 4 * k) * ND + a], ea, acc[k]);
    }
    __syncthreads();
#pragma unroll
    for (int k = 0; k < 16; ++k) V[wq + 4 * k][c] = acc[k];
  }
  __syncthreads();
  {
    float acc[16];
#pragma unroll
    for (int k = 0; k < 16; ++k) acc[k] = 0.f;
    for (int a = 0; a < ND; ++a) {
      float sa = s_g[a * ND + c];
#pragma unroll
      for (int k = 0; k < 16; ++k) acc[k] = fmaf(V[wq + 4 * k][a], sa, acc[k]);
    }
    __syncthreads();
#pragma unroll
    for (int k = 0; k < 16; ++k) A[wq + 4 * k][c] = acc[k];
  }
  __syncthreads();
  for (int e = tid; e < NN; e += 256) V[e >> 6][e & 63] = ((e >> 6) == (e & 63)) ? 1.f : 0.f;
  jacobi2s(A, V, tid);
  if (tid < ND) f1[tid] = 1.f / sqrtf(fmaxf(A[tid][tid], 1e-30f));
  __syncthreads();
  recon_write(V, f1, mi_out, c, wq);
}

// batched: W = mi*x*mi, team eigh -> lam, Aout = ss*U, var partials
__global__ __launch_bounds__(128, 4) void k_stage3(const float* __restrict__ x,
                                                   const float* __restrict__ mi,
                                                   const float* __restrict__ ss,
                                                   float* __restrict__ aout,
                                                   float* __restrict__ lam,
                                                   float* __restrict__ varPart,
                                                   int G3) {
  __shared__ float Xb[4096];
  __shared__ float shr[512];
  __shared__ int   anyf[2];
  int tid = threadIdx.x, lane = tid & 63, wv = tid >> 6;
  float varacc = 0.f;

  for (int i = blockIdx.x; i < NB; i += G3) {
    __syncthreads();
    float w[32];
    congruence_team(x + (size_t)i * NN, mi, Xb, lane, wv, w);
    float s2 = jacobi_team(w, shr, anyf, lane, wv);
    float sig = sqrtf(fmaxf(s2, 1e-38f));
    float inv = 1.f / sig;
    if (wv == 0) {
      lam[(size_t)i * ND + lane] = sig;
      float lg = logf(sig);
      varacc = fmaf(lg, lg, varacc);
    }
    // park U as T[c][e]
#pragma unroll
    for (int g2 = 0; g2 < 8; ++g2) {
      float4 u4 = make_float4(w[4 * g2 + 0] * inv, w[4 * g2 + 1] * inv,
                              w[4 * g2 + 2] * inv, w[4 * g2 + 3] * inv);
      *(float4*)(Xb + swz4(lane, 8 * wv + g2)) = u4;
    }
    __syncthreads();
    // Aout[32wv+r][lane] = sum_a ss[32wv+r][a] * U[a][lane]; U[a][lane] = Xb[lane][a]
    float acc[32];
#pragma unroll
    for (int r = 0; r < 32; ++r) acc[r] = 0.f;
    for (int a = 0; a < 64; ++a) {
      float ua = Xb[swzE(lane, a)];
      const float* ssr = ss + a * 64 + 32 * wv;
#pragma unroll
      for (int r = 0; r < 32; ++r) acc[r] = fmaf(ssr[r], ua, acc[r]);
    }
#pragma unroll
    for (int r = 0; r < 32; ++r)
      aout[(size_t)i * NN + (32 * wv + r) * 64 + lane] = acc[r];
  }
  for (int o = 32; o; o >>= 1) varacc += __shfl_down(varacc, o);
  if (tid == 0) varPart[blockIdx.x] = varacc;
}

__global__ __launch_bounds__(64) void k_pfinal(const float* __restrict__ varPart,
                                               const float* __restrict__ scale,
                                               float* __restrict__ pout, int n) {
  int tid = threadIdx.x;
  float s = 0.f;
  for (int i = tid; i < n; i += 64) s += varPart[i];
  for (int o = 32; o; o >>= 1) s += __shfl_down(s, o);
  if (tid == 0) {
    float var = s * (1.f / (float)NB);
    float sd = sqrtf(var);
    pout[0] = scale[0] / (sd + 1e-5f);
  }
}

__global__ __launch_bounds__(256) void k_stage5(const float* __restrict__ ain,
                                                const float* __restrict__ lam,
                                                const float* __restrict__ pws,
                                                float* __restrict__ out) {
  __shared__ float Ab[ND][PAD];
  __shared__ float lp[ND];
  int tid = threadIdx.x;
  int i = blockIdx.x;
  for (int e = tid; e < NN; e += 256) Ab[e >> 6][e & 63] = ain[(size_t)i * NN + e];
  if (tid < ND) {
    float p = pws[0];
    lp[tid] = powf(lam[(size_t)i * ND + tid], p);
  }
  __syncthreads();
  int c = tid & 63, wq = tid >> 6;
  float acc[16];
#pragma unroll
  for (int k = 0; k < 16; ++k) acc[k] = 0.f;
  for (int j = 0; j < ND; ++j) {
    float m = lp[j] * Ab[c][j];
#pragma unroll
    for (int k = 0; k < 16; ++k) acc[k] = fmaf(Ab[wq + 4 * k][j], m, acc[k]);
  }
#pragma unroll
  for (int k = 0; k < 16; ++k)
    out[(size_t)i * NN + (wq + 4 * k) * ND + c] = acc[k];
}

// ---------------------------------------------------------------------------
extern "C" void kernel_launch(void* const* d_in, const int* in_sizes, int n_in,
                              void* d_out, int out_size, void* d_ws, size_t ws_size,
                              hipStream_t stream) {
  const float* x     = (const float*)d_in[0];
  const float* shift = (const float*)d_in[1];
  const float* scale = (const float*)d_in[2];
  float* out = (float*)d_out;
  float* ws  = (float*)d_ws;
  (void)in_sizes; (void)n_in; (void)out_size;

  size_t wsf = ws_size / 4;
  int G2 = G2_BLOCKS;
  if (OFF_TPART + (size_t)G2 * NN > wsf) {
    size_t avail = (wsf > OFF_TPART) ? (wsf - OFF_TPART) / NN : 1;
    if (avail < 1) avail = 1;
    if (avail < (size_t)G2) G2 = (int)avail;
  }

  k_mean_part<<<dim3(16, 32), 256, 0, stream>>>(x, ws + OFF_MEANPART);
  k_mean_final<<<16, 256, 0, stream>>>(ws + OFF_MEANPART, ws + OFF_MEANA);
  k_prep1<<<2, 256, 0, stream>>>(ws + OFF_MEANA, shift, ws + OFF_S, ws + OFF_SI,
                                 ws + OFF_SS);
  k_stage2<<<G2, 128, 0, stream>>>(x, ws + OFF_SI, ws + OFF_TPART, G2);
  k_reduce_t<<<16, 256, 0, stream>>>(ws + OFF_TPART, ws + OFF_TBAR, G2);
  k_prep2<<<1, 256, 0, stream>>>(ws + OFF_TBAR, ws + OFF_S, ws + OFF_MI);
  k_stage3<<<G3_BLOCKS, 128, 0, stream>>>(x, ws + OFF_MI, ws + OFF_SS, out,
                                          ws + OFF_LAM, ws + OFF_VARPART, G3_BLOCKS);
  k_pfinal<<<1, 64, 0, stream>>>(ws + OFF_VARPART, scale, ws + OFF_P, G3_BLOCKS);
  k_stage5<<<8192, 256, 0, stream>>>(out, ws + OFF_LAM, ws + OFF_P, out);
}

// Round 8
// 30993.909 us; speedup vs baseline: 15.0307x; 15.0307x over previous
//
#include <hip/hip_runtime.h>
#include <math.h>
#include <utility>

#define ND 64
#define PAD 65
#define NN 4096
#define NB 8192

// ws layout (floats)
#define OFF_MEANPART ((size_t)0)        // 32*4096
#define OFF_MEANA    ((size_t)131072)
#define OFF_S        ((size_t)135168)
#define OFF_SI       ((size_t)139264)
#define OFF_SS       ((size_t)143360)
#define OFF_TBAR     ((size_t)147456)
#define OFF_MI       ((size_t)151552)
#define OFF_P        ((size_t)155648)
#define OFF_VARPART  ((size_t)155712)   // 2048 slots
#define OFF_LAM      ((size_t)157760)   // NB*ND = 524288
#define OFF_TPART    ((size_t)682048)   // G2*4096 per-block partials

#define G2_BLOCKS 2048
#define G3_BLOCKS 2048

typedef int v2i __attribute__((ext_vector_type(2)));

// ---------------------------------------------------------------------------
// lane-exchange primitives (all bit-exact)
// ---------------------------------------------------------------------------
template<int CTRL>
__device__ __forceinline__ float dppf(float x) {
  return __builtin_bit_cast(float,
      __builtin_amdgcn_mov_dpp(__builtin_bit_cast(int, x), CTRL, 0xF, 0xF, true));
}
__device__ __forceinline__ float bperm_f(int pa, float x) {
  return __builtin_bit_cast(float,
      __builtin_amdgcn_ds_bpermute(pa, __builtin_bit_cast(int, x)));
}
// lane^16 / lane^32 via permlane*_swap; swap(x,x) gives per-lane the multiset
// {x[lane], x[lane^K]}; A+B-x in integer arithmetic reconstructs x[lane^K]
// exactly regardless of output-order convention.
__device__ __forceinline__ float pl16x(float x) {
  int xi = __builtin_bit_cast(int, x);
  v2i pr = __builtin_amdgcn_permlane16_swap(xi, xi, false, false);
  unsigned r = (unsigned)pr.x + (unsigned)pr.y - (unsigned)xi;
  return __builtin_bit_cast(float, (int)r);
}
__device__ __forceinline__ float pl32x(float x) {
  int xi = __builtin_bit_cast(int, x);
  v2i pr = __builtin_amdgcn_permlane32_swap(xi, xi, false, false);
  unsigned r = (unsigned)pr.x + (unsigned)pr.y - (unsigned)xi;
  return __builtin_bit_cast(float, (int)r);
}

// XOR-distance exchange on the VALU: quad_perm for ^1/^2/^3,
// row_half_mirror=^7, row_mirror=^15, composites for the rest of the low
// nibble (<=3 ops), permlane16/32_swap for bits 16/32.
template<int R>
__device__ __forceinline__ float xorlane(float x) {
  constexpr int lo = R & 15;
  float t = x;
  if constexpr (lo == 1)       t = dppf<0xB1>(t);
  else if constexpr (lo == 2)  t = dppf<0x4E>(t);
  else if constexpr (lo == 3)  t = dppf<0x1B>(t);
  else if constexpr (lo == 4)  { t = dppf<0x141>(t); t = dppf<0x1B>(t); }
  else if constexpr (lo == 5)  { t = dppf<0x141>(t); t = dppf<0x4E>(t); }
  else if constexpr (lo == 6)  { t = dppf<0x141>(t); t = dppf<0xB1>(t); }
  else if constexpr (lo == 7)  t = dppf<0x141>(t);
  else if constexpr (lo == 8)  { t = dppf<0x140>(t); t = dppf<0x141>(t); }
  else if constexpr (lo == 9)  { t = dppf<0x140>(t); t = dppf<0x141>(t); t = dppf<0xB1>(t); }
  else if constexpr (lo == 10) { t = dppf<0x140>(t); t = dppf<0x141>(t); t = dppf<0x4E>(t); }
  else if constexpr (lo == 11) { t = dppf<0x140>(t); t = dppf<0x141>(t); t = dppf<0x1B>(t); }
  else if constexpr (lo == 12) { t = dppf<0x140>(t); t = dppf<0x1B>(t); }
  else if constexpr (lo == 13) { t = dppf<0x140>(t); t = dppf<0x4E>(t); }
  else if constexpr (lo == 14) { t = dppf<0x140>(t); t = dppf<0xB1>(t); }
  else if constexpr (lo == 15) t = dppf<0x140>(t);
  if constexpr (R & 16) t = pl16x(t);
  if constexpr (R & 32) t = pl32x(t);
  return t;
}

constexpr int xlocost(int lo) {
  constexpr int t[16] = {0,1,1,1,2,2,2,1,2,3,3,3,2,2,2,1};
  return t[lo];
}
constexpr int xcost(int R) { return xlocost(R & 15) + ((R >> 4) & 1) + ((R >> 5) & 1); }

// ---------------------------------------------------------------------------
// XOR-swizzled 64x64 LDS tile addressing (float indices).
// ---------------------------------------------------------------------------
__device__ __forceinline__ constexpr int skey(int row) { return (row + (row >> 4)) & 15; }
__device__ __forceinline__ int swz4(int row, int g) { return row * 64 + ((g ^ skey(row)) << 2); }
__device__ __forceinline__ int swzE(int row, int e) {
  return row * 64 + (((e >> 2) ^ skey(row)) << 2) + (e & 3);
}

// ---------------------------------------------------------------------------
// Team Jacobi round (2 waves per matrix; wave wv holds rows [32wv,32wv+32) of
// every column; lane = column). Cross-wave apq via ping-pong LDS share.
// parity alternates between consecutive rounds INCLUDING across sweep
// boundaries. Exactly one barrier per round regardless of rotation decisions.
// ---------------------------------------------------------------------------
template<int R>
__device__ __forceinline__ bool round_step(float (&w)[32], float &g, float* shr,
                                           int parity, int lane, int wv) {
  float v[32]; float gv;
  if constexpr (xcost(R) >= 4) {
    int pa = (lane ^ R) << 2;
#pragma unroll
    for (int i = 0; i < 32; ++i) {
      float t = bperm_f(pa, w[i]);
      asm volatile("" : "+v"(t));
      v[i] = t;
    }
    { float t = bperm_f(pa, g); asm volatile("" : "+v"(t)); gv = t; }
  } else {
#pragma unroll
    for (int i = 0; i < 32; ++i) v[i] = xorlane<R>(w[i]);
    gv = xorlane<R>(g);
  }
  float a0 = 0.f, a1 = 0.f, a2 = 0.f, a3 = 0.f;
#pragma unroll
  for (int i = 0; i < 32; i += 4) {
    a0 = fmaf(w[i + 0], v[i + 0], a0);
    a1 = fmaf(w[i + 1], v[i + 1], a1);
    a2 = fmaf(w[i + 2], v[i + 2], a2);
    a3 = fmaf(w[i + 3], v[i + 3], a3);
  }
  float pd = (a0 + a1) + (a2 + a3);
  shr[(parity * 2 + wv) * 64 + lane] = pd;
  __syncthreads();
  float apq = shr[(parity * 2 + 0) * 64 + lane] + shr[(parity * 2 + 1) * 64 + lane];
  bool rot = (apq * apq > 4e-10f * g * gv);
  if (rot) {
    int partner = lane ^ R;
    bool amP = lane < partner;
    float app = amP ? g : gv;
    float aqq = amP ? gv : g;
    float tau = (aqq - app) / (2.f * apq);
    float t = 1.f / (fabsf(tau) + sqrtf(1.f + tau * tau));
    t = (tau < 0.f) ? -t : t;
    float cr = 1.f / sqrtf(1.f + t * t);
    float sr = t * cr;
    float s2v = amP ? -sr : sr;
#pragma unroll
    for (int i = 0; i < 32; ++i) w[i] = fmaf(s2v, v[i], cr * w[i]);
    float d = t * apq;
    g = amP ? (g - d) : (g + d);
  }
  return __any(rot);
}

template<int... Is>
__device__ __forceinline__ bool sweep_impl(float (&w)[32], float &g, float* shr,
                                           int lane, int wv, int sweep,
                                           std::integer_sequence<int, Is...>) {
  bool any = false;
  // 63 rounds/sweep (odd) -> (sweep + Is) & 1 alternates continuously across
  // sweep boundaries as well as within a sweep.
  ((any = round_step<Is + 1>(w, g, shr, (sweep + Is) & 1, lane, wv) || any), ...);
  return any;
}

// shr slots: 0/1 round ping-pong, 2 init, 3 post (512 floats).
// anyf: 2-int shared flag for BLOCK-UNIFORM sweep termination.
__device__ __forceinline__ float jacobi_team(float (&w)[32], float* shr, int* anyf,
                                             int lane, int wv) {
  float a0 = 0.f, a1 = 0.f, a2 = 0.f, a3 = 0.f;
#pragma unroll
  for (int i = 0; i < 32; i += 4) {
    a0 = fmaf(w[i + 0], w[i + 0], a0);
    a1 = fmaf(w[i + 1], w[i + 1], a1);
    a2 = fmaf(w[i + 2], w[i + 2], a2);
    a3 = fmaf(w[i + 3], w[i + 3], a3);
  }
  float pd = (a0 + a1) + (a2 + a3);
  shr[(2 * 2 + wv) * 64 + lane] = pd;
  __syncthreads();
  float g = shr[(2 * 2 + 0) * 64 + lane] + shr[(2 * 2 + 1) * 64 + lane];
  for (int sweep = 0; sweep < 18; ++sweep) {
    bool any = sweep_impl(w, g, shr, lane, wv, sweep,
                          std::make_integer_sequence<int, 63>{});
    anyf[wv] = any ? 1 : 0;
    __syncthreads();               // also fences last round's shr reads
    int combined = anyf[0] | anyf[1];
    if (!combined) break;          // uniform across both waves by construction
  }
  a0 = a1 = a2 = a3 = 0.f;
#pragma unroll
  for (int i = 0; i < 32; i += 4) {
    a0 = fmaf(w[i + 0], w[i + 0], a0);
    a1 = fmaf(w[i + 1], w[i + 1], a1);
    a2 = fmaf(w[i + 2], w[i + 2], a2);
    a3 = fmaf(w[i + 3], w[i + 3], a3);
  }
  pd = (a0 + a1) + (a2 + a3);
  shr[(3 * 2 + wv) * 64 + lane] = pd;
  __syncthreads();
  return shr[(3 * 2 + 0) * 64 + lane] + shr[(3 * 2 + 1) * 64 + lane];
}

// ---------------------------------------------------------------------------
// Team congruence: M = q*(x*q) for symmetric q; wave wv ends with its half
// rows of M's column `lane` in w[32]. Xb = 4096-float swizzled tile.
// ---------------------------------------------------------------------------
__device__ __forceinline__ void congruence_team(const float* __restrict__ xi,
                                                const float* __restrict__ q,
                                                float* __restrict__ Xb,
                                                int lane, int wv,
                                                float (&w)[32]) {
#pragma unroll
  for (int k = 0; k < 8; ++k) {
    int flat = wv * 2048 + k * 256 + lane * 4;
    float4 rv = *(const float4*)(xi + flat);
    int a = flat >> 6;
    *(float4*)(Xb + swz4(a, lane & 15)) = rv;
  }
  __syncthreads();
  // step1: B[r] = sum_a x[a][32wv+r] * q[a][lane]   (x, q symmetric)
  float B[32];
#pragma unroll
  for (int r = 0; r < 32; ++r) B[r] = 0.f;
  const float* qc = q + lane * 64;
  for (int a4 = 0; a4 < 64; a4 += 4) {
    float4 s4 = *(const float4*)(qc + a4);
#pragma unroll
    for (int t = 0; t < 4; ++t) {
      int a = a4 + t;
      float sa = (t == 0) ? s4.x : (t == 1) ? s4.y : (t == 2) ? s4.z : s4.w;
#pragma unroll
      for (int g2 = 0; g2 < 8; ++g2) {
        float4 xa = *(const float4*)(Xb + swz4(a, 8 * wv + g2));
        B[4 * g2 + 0] = fmaf(xa.x, sa, B[4 * g2 + 0]);
        B[4 * g2 + 1] = fmaf(xa.y, sa, B[4 * g2 + 1]);
        B[4 * g2 + 2] = fmaf(xa.z, sa, B[4 * g2 + 2]);
        B[4 * g2 + 3] = fmaf(xa.w, sa, B[4 * g2 + 3]);
      }
    }
  }
  __syncthreads();
  // park B as T[c][e] = B[e][c]
#pragma unroll
  for (int g2 = 0; g2 < 8; ++g2) {
    float4 b4 = make_float4(B[4 * g2 + 0], B[4 * g2 + 1], B[4 * g2 + 2], B[4 * g2 + 3]);
    *(float4*)(Xb + swz4(lane, 8 * wv + g2)) = b4;
  }
  __syncthreads();
  // step2: w[r] = sum_a q[32wv+r][a] * B[a][lane]
#pragma unroll
  for (int r = 0; r < 32; ++r) w[r] = 0.f;
  for (int a = 0; a < 64; ++a) {
    float ba = Xb[swzE(lane, a)];
    const float* qr = q + a * 64 + 32 * wv;
#pragma unroll
    for (int r = 0; r < 32; ++r) w[r] = fmaf(qr[r], ba, w[r]);
  }
}

// ---------------------------------------------------------------------------
// Two-sided LDS Jacobi (256 threads, one 64x64 matrix) for the few singles.
// ---------------------------------------------------------------------------
__device__ void jacobi2s(float (&A)[ND][PAD], float (&V)[ND][PAD], int tid) {
  __shared__ float cs_[32], sn_[32];
  __shared__ int   pp_[32], qq_[32];
  __shared__ int   rotcnt_;
  __shared__ float fro2_;
  __shared__ float red_[4];

  __syncthreads();
  float loc = 0.f;
  for (int e = tid; e < NN; e += 256) { float a = A[e >> 6][e & 63]; loc += a * a; }
  for (int o = 32; o; o >>= 1) loc += __shfl_down(loc, o);
  if ((tid & 63) == 0) red_[tid >> 6] = loc;
  __syncthreads();
  if (tid == 0) fro2_ = red_[0] + red_[1] + red_[2] + red_[3];
  __syncthreads();
  float fro2 = fro2_;

  for (int sweep = 0; sweep < 20; ++sweep) {
    if (tid == 0) rotcnt_ = 0;
    __syncthreads();
    for (int r = 0; r < 63; ++r) {
      if (tid < 32) {
        int p, q;
        if (tid == 0) { p = 63; q = r; }
        else { p = (r + tid) % 63; q = (r + 63 - tid) % 63; }
        if (p > q) { int t0 = p; p = q; q = t0; }
        pp_[tid] = p; qq_[tid] = q;
        float app = A[p][p], aqq = A[q][q], apq = A[p][q];
        float thr = fmaxf(1e-12f * fabsf(app * aqq), 1e-14f * fro2);
        float c = 1.f, s = 0.f;
        if (apq * apq > thr) {
          float tau = (aqq - app) / (2.f * apq);
          float t = 1.f / (fabsf(tau) + sqrtf(1.f + tau * tau));
          t = (tau < 0.f) ? -t : t;
          c = 1.f / sqrtf(1.f + t * t);
          s = t * c;
          atomicAdd(&rotcnt_, 1);
        }
        cs_[tid] = c; sn_[tid] = s;
      }
      __syncthreads();
      for (int t = tid; t < 2048; t += 256) {
        int k = t >> 6, j = t & 63;
        int p = pp_[k], q = qq_[k]; float c = cs_[k], s = sn_[k];
        float ap = A[p][j], aq = A[q][j];
        A[p][j] = c * ap - s * aq;
        A[q][j] = s * ap + c * aq;
      }
      __syncthreads();
      for (int t = tid; t < 4096; t += 256) {
        int k = (t >> 6) & 31, j = t & 63;
        int p = pp_[k], q = qq_[k]; float c = cs_[k], s = sn_[k];
        if (t < 2048) {
          float ap = A[j][p], aq = A[j][q];
          A[j][p] = c * ap - s * aq;
          A[j][q] = s * ap + c * aq;
        } else {
          float vp = V[j][p], vq = V[j][q];
          V[j][p] = c * vp - s * vq;
          V[j][q] = s * vp + c * vq;
        }
      }
      __syncthreads();
    }
    int rc = rotcnt_;
    __syncthreads();
    if (rc == 0) break;
  }
}

__device__ void recon_write(const float (&V)[ND][PAD], const float* f, float* g,
                            int c, int wq) {
  float acc[16];
#pragma unroll
  for (int k = 0; k < 16; ++k) acc[k] = 0.f;
  for (int j = 0; j < ND; ++j) {
    float m = f[j] * V[c][j];
#pragma unroll
    for (int k = 0; k < 16; ++k) acc[k] = fmaf(V[wq + 4 * k][j], m, acc[k]);
  }
#pragma unroll
  for (int k = 0; k < 16; ++k) g[(wq + 4 * k) * ND + c] = acc[k];
}

// ---------------------------------------------------------------------------
// Kernels
// ---------------------------------------------------------------------------
__global__ __launch_bounds__(256) void k_mean_part(const float* __restrict__ x,
                                                   float* __restrict__ part) {
  int e = blockIdx.x * 256 + threadIdx.x;
  int chunk = blockIdx.y;
  const float* px = x + (size_t)chunk * 256 * NN + e;
  float s = 0.f;
  for (int i = 0; i < 256; ++i) s += px[(size_t)i * NN];
  part[(size_t)chunk * NN + e] = s;
}

__global__ __launch_bounds__(256) void k_mean_final(const float* __restrict__ part,
                                                    float* __restrict__ meanA) {
  int e = blockIdx.x * 256 + threadIdx.x;
  float s = 0.f;
  for (int c = 0; c < 32; ++c) s += part[(size_t)c * NN + e];
  meanA[e] = s * (1.f / (float)NB);
}

__global__ __launch_bounds__(256) void k_prep1(const float* __restrict__ meanA,
                                               const float* __restrict__ shift,
                                               float* __restrict__ s_out,
                                               float* __restrict__ si_out,
                                               float* __restrict__ ss_out) {
  __shared__ float A[ND][PAD], V[ND][PAD];
  __shared__ float f1[ND], f2[ND];
  int tid = threadIdx.x;
  const float* src = (blockIdx.x == 0) ? meanA : shift;
  for (int e = tid; e < NN; e += 256) A[e >> 6][e & 63] = src[e];
  for (int e = tid; e < NN; e += 256) V[e >> 6][e & 63] = ((e >> 6) == (e & 63)) ? 1.f : 0.f;
  jacobi2s(A, V, tid);
  if (tid < ND) {
    float wv = fmaxf(A[tid][tid], 1e-30f);
    f1[tid] = sqrtf(wv);
    f2[tid] = 1.f / sqrtf(wv);
  }
  __syncthreads();
  int c = tid & 63, wq = tid >> 6;
  if (blockIdx.x == 0) {
    recon_write(V, f1, s_out, c, wq);
    recon_write(V, f2, si_out, c, wq);
  } else {
    recon_write(V, f1, ss_out, c, wq);
  }
}

// batched Karcher tangent accumulation: 2 waves per matrix.
// launch_bounds (128,2): empirically gives the 128-VGPR budget this kernel
// was sized for (live set ~115). (128,4) capped VGPRs at 64 -> 735 GB of
// scratch spill traffic and 275 ms (round-7 counters).
__global__ __launch_bounds__(128, 2) void k_stage2(const float* __restrict__ x,
                                                   const float* __restrict__ si,
                                                   float* __restrict__ tPart,
                                                   int G2) {
  __shared__ float Xb[4096];
  __shared__ float shr[512];
  __shared__ float lw[64];
  __shared__ int   anyf[2];
  int tid = threadIdx.x, lane = tid & 63, wv = tid >> 6;

  float tacc[32];
#pragma unroll
  for (int i = 0; i < 32; ++i) tacc[i] = 0.f;

  for (int i = blockIdx.x; i < NB; i += G2) {
    __syncthreads();
    float w[32];
    congruence_team(x + (size_t)i * NN, si, Xb, lane, wv, w);
    float s2 = jacobi_team(w, shr, anyf, lane, wv);
    float sig = sqrtf(fmaxf(s2, 1e-38f));
    float inv = 1.f / sig;
    if (wv == 0) lw[lane] = logf(sig);
    // park U as T[c][e] = U[e][c]  (row c of Xb = eigenvector u_c)
#pragma unroll
    for (int g2 = 0; g2 < 8; ++g2) {
      float4 u4 = make_float4(w[4 * g2 + 0] * inv, w[4 * g2 + 1] * inv,
                              w[4 * g2 + 2] * inv, w[4 * g2 + 3] * inv);
      *(float4*)(Xb + swz4(lane, 8 * wv + g2)) = u4;
    }
    __syncthreads();
    // t[r][lane] += lw[j] * (u_j)_lane * (u_j)_r
    for (int j = 0; j < 64; ++j) {
      float ucj = Xb[swzE(j, lane)];
      float m = lw[j] * ucj;
#pragma unroll
      for (int g2 = 0; g2 < 8; ++g2) {
        float4 u4 = *(const float4*)(Xb + swz4(j, 8 * wv + g2));
        tacc[4 * g2 + 0] = fmaf(u4.x, m, tacc[4 * g2 + 0]);
        tacc[4 * g2 + 1] = fmaf(u4.y, m, tacc[4 * g2 + 1]);
        tacc[4 * g2 + 2] = fmaf(u4.z, m, tacc[4 * g2 + 2]);
        tacc[4 * g2 + 3] = fmaf(u4.w, m, tacc[4 * g2 + 3]);
      }
    }
  }
#pragma unroll
  for (int r = 0; r < 32; ++r)
    tPart[(size_t)blockIdx.x * NN + (32 * wv + r) * 64 + lane] = tacc[r];
}

__global__ __launch_bounds__(256) void k_reduce_t(const float* __restrict__ tPart,
                                                  float* __restrict__ tbar, int nw) {
  int e = blockIdx.x * 256 + threadIdx.x;
  float s = 0.f;
  for (int b = 0; b < nw; ++b) s += tPart[(size_t)b * NN + e];
  tbar[e] = s * (1.f / (float)NB);
}

__global__ __launch_bounds__(256) void k_prep2(const float* __restrict__ tbar,
                                               const float* __restrict__ s_g,
                                               float* __restrict__ mi_out) {
  __shared__ float A[ND][PAD], V[ND][PAD];
  __shared__ float f1[ND];
  int tid = threadIdx.x;
  int c = tid & 63, wq = tid >> 6;
  for (int e = tid; e < NN; e += 256) A[e >> 6][e & 63] = tbar[e];
  for (int e = tid; e < NN; e += 256) V[e >> 6][e & 63] = ((e >> 6) == (e & 63)) ? 1.f : 0.f;
  jacobi2s(A, V, tid);
  if (tid < ND) f1[tid] = expf(A[tid][tid]);
  __syncthreads();
  {
    float acc[16];
#pragma unroll
    for (int k = 0; k < 16; ++k) acc[k] = 0.f;
    for (int j = 0; j < ND; ++j) {
      float m = f1[j] * V[c][j];
#pragma unroll
      for (int k = 0; k < 16; ++k) acc[k] = fmaf(V[wq + 4 * k][j], m, acc[k]);
    }
    __syncthreads();
#pragma unroll
    for (int k = 0; k < 16; ++k) A[wq + 4 * k][c] = acc[k];
  }
  __syncthreads();
  {
    float acc[16];
#pragma unroll
    for (int k = 0; k < 16; ++k) acc[k] = 0.f;
    for (int a = 0; a < ND; ++a) {
      float ea = A[a][c];
#pragma unroll
      for (int k = 0; k < 16; ++k) acc[k] = fmaf(s_g[(wq + 4 * k) * ND + a], ea, acc[k]);
    }
    __syncthreads();
#pragma unroll
    for (int k = 0; k < 16; ++k) V[wq + 4 * k][c] = acc[k];
  }
  __syncthreads();
  {
    float acc[16];
#pragma unroll
    for (int k = 0; k < 16; ++k) acc[k] = 0.f;
    for (int a = 0; a < ND; ++a) {
      float sa = s_g[a * ND + c];
#pragma unroll
      for (int k = 0; k < 16; ++k) acc[k] = fmaf(V[wq + 4 * k][a], sa, acc[k]);
    }
    __syncthreads();
#pragma unroll
    for (int k = 0; k < 16; ++k) A[wq + 4 * k][c] = acc[k];
  }
  __syncthreads();
  for (int e = tid; e < NN; e += 256) V[e >> 6][e & 63] = ((e >> 6) == (e & 63)) ? 1.f : 0.f;
  jacobi2s(A, V, tid);
  if (tid < ND) f1[tid] = 1.f / sqrtf(fmaxf(A[tid][tid], 1e-30f));
  __syncthreads();
  recon_write(V, f1, mi_out, c, wq);
}

// batched: W = mi*x*mi, team eigh -> lam, Aout = ss*U, var partials
__global__ __launch_bounds__(128, 2) void k_stage3(const float* __restrict__ x,
                                                   const float* __restrict__ mi,
                                                   const float* __restrict__ ss,
                                                   float* __restrict__ aout,
                                                   float* __restrict__ lam,
                                                   float* __restrict__ varPart,
                                                   int G3) {
  __shared__ float Xb[4096];
  __shared__ float shr[512];
  __shared__ int   anyf[2];
  int tid = threadIdx.x, lane = tid & 63, wv = tid >> 6;
  float varacc = 0.f;

  for (int i = blockIdx.x; i < NB; i += G3) {
    __syncthreads();
    float w[32];
    congruence_team(x + (size_t)i * NN, mi, Xb, lane, wv, w);
    float s2 = jacobi_team(w, shr, anyf, lane, wv);
    float sig = sqrtf(fmaxf(s2, 1e-38f));
    float inv = 1.f / sig;
    if (wv == 0) {
      lam[(size_t)i * ND + lane] = sig;
      float lg = logf(sig);
      varacc = fmaf(lg, lg, varacc);
    }
    // park U as T[c][e]
#pragma unroll
    for (int g2 = 0; g2 < 8; ++g2) {
      float4 u4 = make_float4(w[4 * g2 + 0] * inv, w[4 * g2 + 1] * inv,
                              w[4 * g2 + 2] * inv, w[4 * g2 + 3] * inv);
      *(float4*)(Xb + swz4(lane, 8 * wv + g2)) = u4;
    }
    __syncthreads();
    // Aout[32wv+r][lane] = sum_a ss[32wv+r][a] * U[a][lane]; U[a][lane] = Xb[lane][a]
    float acc[32];
#pragma unroll
    for (int r = 0; r < 32; ++r) acc[r] = 0.f;
    for (int a = 0; a < 64; ++a) {
      float ua = Xb[swzE(lane, a)];
      const float* ssr = ss + a * 64 + 32 * wv;
#pragma unroll
      for (int r = 0; r < 32; ++r) acc[r] = fmaf(ssr[r], ua, acc[r]);
    }
#pragma unroll
    for (int r = 0; r < 32; ++r)
      aout[(size_t)i * NN + (32 * wv + r) * 64 + lane] = acc[r];
  }
  for (int o = 32; o; o >>= 1) varacc += __shfl_down(varacc, o);
  if (tid == 0) varPart[blockIdx.x] = varacc;
}

__global__ __launch_bounds__(64) void k_pfinal(const float* __restrict__ varPart,
                                               const float* __restrict__ scale,
                                               float* __restrict__ pout, int n) {
  int tid = threadIdx.x;
  float s = 0.f;
  for (int i = tid; i < n; i += 64) s += varPart[i];
  for (int o = 32; o; o >>= 1) s += __shfl_down(s, o);
  if (tid == 0) {
    float var = s * (1.f / (float)NB);
    float sd = sqrtf(var);
    pout[0] = scale[0] / (sd + 1e-5f);
  }
}

__global__ __launch_bounds__(256) void k_stage5(const float* __restrict__ ain,
                                                const float* __restrict__ lam,
                                                const float* __restrict__ pws,
                                                float* __restrict__ out) {
  __shared__ float Ab[ND][PAD];
  __shared__ float lp[ND];
  int tid = threadIdx.x;
  int i = blockIdx.x;
  for (int e = tid; e < NN; e += 256) Ab[e >> 6][e & 63] = ain[(size_t)i * NN + e];
  if (tid < ND) {
    float p = pws[0];
    lp[tid] = powf(lam[(size_t)i * ND + tid], p);
  }
  __syncthreads();
  int c = tid & 63, wq = tid >> 6;
  float acc[16];
#pragma unroll
  for (int k = 0; k < 16; ++k) acc[k] = 0.f;
  for (int j = 0; j < ND; ++j) {
    float m = lp[j] * Ab[c][j];
#pragma unroll
    for (int k = 0; k < 16; ++k) acc[k] = fmaf(Ab[wq + 4 * k][j], m, acc[k]);
  }
#pragma unroll
  for (int k = 0; k < 16; ++k)
    out[(size_t)i * NN + (wq + 4 * k) * ND + c] = acc[k];
}

// ---------------------------------------------------------------------------
extern "C" void kernel_launch(void* const* d_in, const int* in_sizes, int n_in,
                              void* d_out, int out_size, void* d_ws, size_t ws_size,
                              hipStream_t stream) {
  const float* x     = (const float*)d_in[0];
  const float* shift = (const float*)d_in[1];
  const float* scale = (const float*)d_in[2];
  float* out = (float*)d_out;
  float* ws  = (float*)d_ws;
  (void)in_sizes; (void)n_in; (void)out_size;

  size_t wsf = ws_size / 4;
  int G2 = G2_BLOCKS;
  if (OFF_TPART + (size_t)G2 * NN > wsf) {
    size_t avail = (wsf > OFF_TPART) ? (wsf - OFF_TPART) / NN : 1;
    if (avail < 1) avail = 1;
    if (avail < (size_t)G2) G2 = (int)avail;
  }

  k_mean_part<<<dim3(16, 32), 256, 0, stream>>>(x, ws + OFF_MEANPART);
  k_mean_final<<<16, 256, 0, stream>>>(ws + OFF_MEANPART, ws + OFF_MEANA);
  k_prep1<<<2, 256, 0, stream>>>(ws + OFF_MEANA, shift, ws + OFF_S, ws + OFF_SI,
                                 ws + OFF_SS);
  k_stage2<<<G2, 128, 0, stream>>>(x, ws + OFF_SI, ws + OFF_TPART, G2);
  k_reduce_t<<<16, 256, 0, stream>>>(ws + OFF_TPART, ws + OFF_TBAR, G2);
  k_prep2<<<1, 256, 0, stream>>>(ws + OFF_TBAR, ws + OFF_S, ws + OFF_MI);
  k_stage3<<<G3_BLOCKS, 128, 0, stream>>>(x, ws + OFF_MI, ws + OFF_SS, out,
                                          ws + OFF_LAM, ws + OFF_VARPART, G3_BLOCKS);
  k_pfinal<<<1, 64, 0, stream>>>(ws + OFF_VARPART, scale, ws + OFF_P, G3_BLOCKS);
  k_stage5<<<8192, 256, 0, stream>>>(out, ws + OFF_LAM, ws + OFF_P, out);
}

// Round 9
// 16292.143 us; speedup vs baseline: 28.5942x; 1.9024x over previous
//
#include <hip/hip_runtime.h>
#include <math.h>

#define ND 64
#define PAD 65
#define NN 4096
#define NB 8192

// ws layout (floats)
#define OFF_MEANPART ((size_t)0)        // 32*4096
#define OFF_MEANA    ((size_t)131072)
#define OFF_S        ((size_t)135168)
#define OFF_SI       ((size_t)139264)
#define OFF_SS       ((size_t)143360)
#define OFF_TBAR     ((size_t)147456)
#define OFF_MI       ((size_t)151552)
#define OFF_P        ((size_t)155648)
#define OFF_VARPART  ((size_t)155712)   // 2048 slots
#define OFF_LAM      ((size_t)157760)   // NB*ND = 524288
#define OFF_TPART    ((size_t)682048)   // G2*4096 per-block partials

#define G2_BLOCKS 2048
#define G3_BLOCKS 2048

// ---------------------------------------------------------------------------
__device__ __forceinline__ float bperm_f(int pa, float x) {
  return __builtin_bit_cast(float,
      __builtin_amdgcn_ds_bpermute(pa, __builtin_bit_cast(int, x)));
}

// XOR-swizzled 64x64 LDS tile addressing (float indices).
__device__ __forceinline__ constexpr int skey(int row) { return (row + (row >> 4)) & 15; }
__device__ __forceinline__ int swz4(int row, int g) { return row * 64 + ((g ^ skey(row)) << 2); }
__device__ __forceinline__ int swzE(int row, int e) {
  return row * 64 + (((e >> 2) ^ skey(row)) << 2) + (e & 3);
}

// ---------------------------------------------------------------------------
// One-sided Jacobi, single wave per matrix, lane = column, w[64] = own column.
// Runtime XOR-tournament loop (small code, I-cache resident), ds_bpermute
// exchange with asm-pinned results (forbids rematerialization = the round-1
// DS double-issue). No barriers: wave-synchronous. Returns ||w||^2 (= sigma^2).
// Requires the 256-VGPR budget of __launch_bounds__(64,1).
// ---------------------------------------------------------------------------
__device__ float jacobi1s64(float (&w)[ND], int lane) {
  float a0 = 0.f, a1 = 0.f, a2 = 0.f, a3 = 0.f;
#pragma unroll
  for (int i = 0; i < ND; i += 4) {
    a0 = fmaf(w[i + 0], w[i + 0], a0);
    a1 = fmaf(w[i + 1], w[i + 1], a1);
    a2 = fmaf(w[i + 2], w[i + 2], a2);
    a3 = fmaf(w[i + 3], w[i + 3], a3);
  }
  float g = (a0 + a1) + (a2 + a3);

  for (int sweep = 0; sweep < 18; ++sweep) {
    bool any = false;
    for (int r = 1; r < ND; ++r) {
      int pa = (lane ^ r) << 2;
      float v[ND + 1];  // v[64] = partner's g
#pragma unroll
      for (int i = 0; i <= ND; ++i) {
        float t = bperm_f(pa, (i < ND) ? w[i] : g);
        asm volatile("" : "+v"(t));  // pin: keep live, never re-issue
        v[i] = t;
      }
      float gv = v[ND];
      float b0 = 0.f, b1 = 0.f, b2 = 0.f, b3 = 0.f;
#pragma unroll
      for (int i = 0; i < ND; i += 4) {
        b0 = fmaf(w[i + 0], v[i + 0], b0);
        b1 = fmaf(w[i + 1], v[i + 1], b1);
        b2 = fmaf(w[i + 2], v[i + 2], b2);
        b3 = fmaf(w[i + 3], v[i + 3], b3);
      }
      float apq = (b0 + b1) + (b2 + b3);
      if (apq * apq > 4e-10f * g * gv) {
        int partner = lane ^ r;
        bool amP = lane < partner;
        float app = amP ? g : gv;
        float aqq = amP ? gv : g;
        float tau = (aqq - app) / (2.f * apq);
        float t = 1.f / (fabsf(tau) + sqrtf(1.f + tau * tau));
        t = (tau < 0.f) ? -t : t;
        float c = 1.f / sqrtf(1.f + t * t);
        float s = t * c;
        float s2v = amP ? -s : s;
#pragma unroll
        for (int i = 0; i < ND; ++i) w[i] = fmaf(s2v, v[i], c * w[i]);
        float d = t * apq;
        g = amP ? (g - d) : (g + d);
        any = true;
      }
    }
    if (!__any(any)) break;
  }
  a0 = a1 = a2 = a3 = 0.f;
#pragma unroll
  for (int i = 0; i < ND; i += 4) {
    a0 = fmaf(w[i + 0], w[i + 0], a0);
    a1 = fmaf(w[i + 1], w[i + 1], a1);
    a2 = fmaf(w[i + 2], w[i + 2], a2);
    a3 = fmaf(w[i + 3], w[i + 3], a3);
  }
  return (a0 + a1) + (a2 + a3);
}

// ---------------------------------------------------------------------------
// Single-wave congruence M = q*(x*q), q symmetric; lane = column of M -> w[64].
// Xb = per-wave 4096-float swizzled tile (x staged, then B^T parked).
// ---------------------------------------------------------------------------
__device__ __forceinline__ void congruence1(const float* __restrict__ xi,
                                            const float* __restrict__ q,
                                            float* __restrict__ Xb, int lane,
                                            float (&w)[ND]) {
  // stage x: 16 coalesced float4 per lane, swizzled row writes
#pragma unroll
  for (int k = 0; k < 16; ++k) {
    int flat = k * 256 + lane * 4;
    float4 rv = *(const float4*)(xi + flat);
    int a = flat >> 6;
    *(float4*)(Xb + swz4(a, lane & 15)) = rv;
  }
  __syncthreads();
  // step1: B[r] = sum_a x[a][r] * q[a][lane]   (x symmetric; row reads broadcast)
  float B[ND];
#pragma unroll
  for (int r = 0; r < ND; ++r) B[r] = 0.f;
  const float* qc = q + lane * ND;
  for (int a = 0; a < ND; ++a) {
    float sa = qc[a];  // q[a][lane] = q[lane][a] (symmetric), coalesced per lane
#pragma unroll
    for (int g2 = 0; g2 < 16; ++g2) {
      float4 xa = *(const float4*)(Xb + swz4(a, g2));
      B[4 * g2 + 0] = fmaf(xa.x, sa, B[4 * g2 + 0]);
      B[4 * g2 + 1] = fmaf(xa.y, sa, B[4 * g2 + 1]);
      B[4 * g2 + 2] = fmaf(xa.z, sa, B[4 * g2 + 2]);
      B[4 * g2 + 3] = fmaf(xa.w, sa, B[4 * g2 + 3]);
    }
  }
  __syncthreads();
  // park own B column as row `lane` (lane-local readback; rule-#20 safe indexing)
#pragma unroll
  for (int g2 = 0; g2 < 16; ++g2) {
    float4 b4 = make_float4(B[4 * g2 + 0], B[4 * g2 + 1], B[4 * g2 + 2], B[4 * g2 + 3]);
    *(float4*)(Xb + swz4(lane, g2)) = b4;
  }
  // step2: w[r] = sum_a q[r][a] * B[a][lane]; B[a][lane] = Xb[row lane][a]
#pragma unroll
  for (int r = 0; r < ND; ++r) w[r] = 0.f;
  for (int a = 0; a < ND; ++a) {
    float ba = Xb[swzE(lane, a)];
    const float* qr = q + a * ND;  // row a (uniform -> scalar loads)
#pragma unroll
    for (int r = 0; r < ND; ++r) w[r] = fmaf(qr[r], ba, w[r]);
  }
}

// ---------------------------------------------------------------------------
// Two-sided LDS Jacobi (256 threads, one 64x64 matrix) for the few singles.
// ---------------------------------------------------------------------------
__device__ void jacobi2s(float (&A)[ND][PAD], float (&V)[ND][PAD], int tid) {
  __shared__ float cs_[32], sn_[32];
  __shared__ int   pp_[32], qq_[32];
  __shared__ int   rotcnt_;
  __shared__ float fro2_;
  __shared__ float red_[4];

  __syncthreads();
  float loc = 0.f;
  for (int e = tid; e < NN; e += 256) { float a = A[e >> 6][e & 63]; loc += a * a; }
  for (int o = 32; o; o >>= 1) loc += __shfl_down(loc, o);
  if ((tid & 63) == 0) red_[tid >> 6] = loc;
  __syncthreads();
  if (tid == 0) fro2_ = red_[0] + red_[1] + red_[2] + red_[3];
  __syncthreads();
  float fro2 = fro2_;

  for (int sweep = 0; sweep < 20; ++sweep) {
    if (tid == 0) rotcnt_ = 0;
    __syncthreads();
    for (int r = 0; r < 63; ++r) {
      if (tid < 32) {
        int p, q;
        if (tid == 0) { p = 63; q = r; }
        else { p = (r + tid) % 63; q = (r + 63 - tid) % 63; }
        if (p > q) { int t0 = p; p = q; q = t0; }
        pp_[tid] = p; qq_[tid] = q;
        float app = A[p][p], aqq = A[q][q], apq = A[p][q];
        float thr = fmaxf(1e-12f * fabsf(app * aqq), 1e-14f * fro2);
        float c = 1.f, s = 0.f;
        if (apq * apq > thr) {
          float tau = (aqq - app) / (2.f * apq);
          float t = 1.f / (fabsf(tau) + sqrtf(1.f + tau * tau));
          t = (tau < 0.f) ? -t : t;
          c = 1.f / sqrtf(1.f + t * t);
          s = t * c;
          atomicAdd(&rotcnt_, 1);
        }
        cs_[tid] = c; sn_[tid] = s;
      }
      __syncthreads();
      for (int t = tid; t < 2048; t += 256) {
        int k = t >> 6, j = t & 63;
        int p = pp_[k], q = qq_[k]; float c = cs_[k], s = sn_[k];
        float ap = A[p][j], aq = A[q][j];
        A[p][j] = c * ap - s * aq;
        A[q][j] = s * ap + c * aq;
      }
      __syncthreads();
      for (int t = tid; t < 4096; t += 256) {
        int k = (t >> 6) & 31, j = t & 63;
        int p = pp_[k], q = qq_[k]; float c = cs_[k], s = sn_[k];
        if (t < 2048) {
          float ap = A[j][p], aq = A[j][q];
          A[j][p] = c * ap - s * aq;
          A[j][q] = s * ap + c * aq;
        } else {
          float vp = V[j][p], vq = V[j][q];
          V[j][p] = c * vp - s * vq;
          V[j][q] = s * vp + c * vq;
        }
      }
      __syncthreads();
    }
    int rc = rotcnt_;
    __syncthreads();
    if (rc == 0) break;
  }
}

__device__ void recon_write(const float (&V)[ND][PAD], const float* f, float* g,
                            int c, int wq) {
  float acc[16];
#pragma unroll
  for (int k = 0; k < 16; ++k) acc[k] = 0.f;
  for (int j = 0; j < ND; ++j) {
    float m = f[j] * V[c][j];
#pragma unroll
    for (int k = 0; k < 16; ++k) acc[k] = fmaf(V[wq + 4 * k][j], m, acc[k]);
  }
#pragma unroll
  for (int k = 0; k < 16; ++k) g[(wq + 4 * k) * ND + c] = acc[k];
}

// ---------------------------------------------------------------------------
// Kernels
// ---------------------------------------------------------------------------
__global__ __launch_bounds__(256) void k_mean_part(const float* __restrict__ x,
                                                   float* __restrict__ part) {
  int e = blockIdx.x * 256 + threadIdx.x;
  int chunk = blockIdx.y;
  const float* px = x + (size_t)chunk * 256 * NN + e;
  float s = 0.f;
  for (int i = 0; i < 256; ++i) s += px[(size_t)i * NN];
  part[(size_t)chunk * NN + e] = s;
}

__global__ __launch_bounds__(256) void k_mean_final(const float* __restrict__ part,
                                                    float* __restrict__ meanA) {
  int e = blockIdx.x * 256 + threadIdx.x;
  float s = 0.f;
  for (int c = 0; c < 32; ++c) s += part[(size_t)c * NN + e];
  meanA[e] = s * (1.f / (float)NB);
}

__global__ __launch_bounds__(256) void k_prep1(const float* __restrict__ meanA,
                                               const float* __restrict__ shift,
                                               float* __restrict__ s_out,
                                               float* __restrict__ si_out,
                                               float* __restrict__ ss_out) {
  __shared__ float A[ND][PAD], V[ND][PAD];
  __shared__ float f1[ND], f2[ND];
  int tid = threadIdx.x;
  const float* src = (blockIdx.x == 0) ? meanA : shift;
  for (int e = tid; e < NN; e += 256) A[e >> 6][e & 63] = src[e];
  for (int e = tid; e < NN; e += 256) V[e >> 6][e & 63] = ((e >> 6) == (e & 63)) ? 1.f : 0.f;
  jacobi2s(A, V, tid);
  if (tid < ND) {
    float wv = fmaxf(A[tid][tid], 1e-30f);
    f1[tid] = sqrtf(wv);
    f2[tid] = 1.f / sqrtf(wv);
  }
  __syncthreads();
  int c = tid & 63, wq = tid >> 6;
  if (blockIdx.x == 0) {
    recon_write(V, f1, s_out, c, wq);
    recon_write(V, f2, si_out, c, wq);
  } else {
    recon_write(V, f1, ss_out, c, wq);
  }
}

// batched Karcher tangent accumulation: ONE WAVE per matrix, 256-VGPR budget.
__global__ __launch_bounds__(64, 1) void k_stage2(const float* __restrict__ x,
                                                  const float* __restrict__ si,
                                                  float* __restrict__ tPart,
                                                  int G2) {
  __shared__ float Xb[4096];
  int lane = threadIdx.x;

  float tacc[ND];
#pragma unroll
  for (int i = 0; i < ND; ++i) tacc[i] = 0.f;

  for (int i = blockIdx.x; i < NB; i += G2) {
    __syncthreads();  // previous tangent reads of Xb done before restaging
    float w[ND];
    congruence1(x + (size_t)i * NN, si, Xb, lane, w);
    float s2 = jacobi1s64(w, lane);
    float sig = sqrtf(fmaxf(s2, 1e-38f));
    float inv = 1.f / sig;
    float lg = logf(sig);
    // park U^T: row c of Xb = eigenvector u_c (lane's own normalized column)
#pragma unroll
    for (int g2 = 0; g2 < 16; ++g2) {
      float4 u4 = make_float4(w[4 * g2 + 0] * inv, w[4 * g2 + 1] * inv,
                              w[4 * g2 + 2] * inv, w[4 * g2 + 3] * inv);
      *(float4*)(Xb + swz4(lane, g2)) = u4;
    }
    __syncthreads();
    // tacc[r] += log(lam_j) * (u_j)_lane * (u_j)_r
    for (int j = 0; j < ND; ++j) {
      float lwj = __shfl(lg, j);
      float uj = Xb[swzE(j, lane)];
      float m = lwj * uj;
#pragma unroll
      for (int g2 = 0; g2 < 16; ++g2) {
        float4 u4 = *(const float4*)(Xb + swz4(j, g2));
        tacc[4 * g2 + 0] = fmaf(u4.x, m, tacc[4 * g2 + 0]);
        tacc[4 * g2 + 1] = fmaf(u4.y, m, tacc[4 * g2 + 1]);
        tacc[4 * g2 + 2] = fmaf(u4.z, m, tacc[4 * g2 + 2]);
        tacc[4 * g2 + 3] = fmaf(u4.w, m, tacc[4 * g2 + 3]);
      }
    }
  }
#pragma unroll
  for (int r = 0; r < ND; ++r)
    tPart[(size_t)blockIdx.x * NN + r * ND + lane] = tacc[r];
}

__global__ __launch_bounds__(256) void k_reduce_t(const float* __restrict__ tPart,
                                                  float* __restrict__ tbar, int nw) {
  int e = blockIdx.x * 256 + threadIdx.x;
  float s = 0.f;
  for (int b = 0; b < nw; ++b) s += tPart[(size_t)b * NN + e];
  tbar[e] = s * (1.f / (float)NB);
}

__global__ __launch_bounds__(256) void k_prep2(const float* __restrict__ tbar,
                                               const float* __restrict__ s_g,
                                               float* __restrict__ mi_out) {
  __shared__ float A[ND][PAD], V[ND][PAD];
  __shared__ float f1[ND];
  int tid = threadIdx.x;
  int c = tid & 63, wq = tid >> 6;
  for (int e = tid; e < NN; e += 256) A[e >> 6][e & 63] = tbar[e];
  for (int e = tid; e < NN; e += 256) V[e >> 6][e & 63] = ((e >> 6) == (e & 63)) ? 1.f : 0.f;
  jacobi2s(A, V, tid);
  if (tid < ND) f1[tid] = expf(A[tid][tid]);
  __syncthreads();
  {
    float acc[16];
#pragma unroll
    for (int k = 0; k < 16; ++k) acc[k] = 0.f;
    for (int j = 0; j < ND; ++j) {
      float m = f1[j] * V[c][j];
#pragma unroll
      for (int k = 0; k < 16; ++k) acc[k] = fmaf(V[wq + 4 * k][j], m, acc[k]);
    }
    __syncthreads();
#pragma unroll
    for (int k = 0; k < 16; ++k) A[wq + 4 * k][c] = acc[k];
  }
  __syncthreads();
  {
    float acc[16];
#pragma unroll
    for (int k = 0; k < 16; ++k) acc[k] = 0.f;
    for (int a = 0; a < ND; ++a) {
      float ea = A[a][c];
#pragma unroll
      for (int k = 0; k < 16; ++k) acc[k] = fmaf(s_g[(wq + 4 * k) * ND + a], ea, acc[k]);
    }
    __syncthreads();
#pragma unroll
    for (int k = 0; k < 16; ++k) V[wq + 4 * k][c] = acc[k];
  }
  __syncthreads();
  {
    float acc[16];
#pragma unroll
    for (int k = 0; k < 16; ++k) acc[k] = 0.f;
    for (int a = 0; a < ND; ++a) {
      float sa = s_g[a * ND + c];
#pragma unroll
      for (int k = 0; k < 16; ++k) acc[k] = fmaf(V[wq + 4 * k][a], sa, acc[k]);
    }
    __syncthreads();
#pragma unroll
    for (int k = 0; k < 16; ++k) A[wq + 4 * k][c] = acc[k];
  }
  __syncthreads();
  for (int e = tid; e < NN; e += 256) V[e >> 6][e & 63] = ((e >> 6) == (e & 63)) ? 1.f : 0.f;
  jacobi2s(A, V, tid);
  if (tid < ND) f1[tid] = 1.f / sqrtf(fmaxf(A[tid][tid], 1e-30f));
  __syncthreads();
  recon_write(V, f1, mi_out, c, wq);
}

// batched: W = mi*x*mi, single-wave eigh -> lam, Aout = ss*U, var partials
__global__ __launch_bounds__(64, 1) void k_stage3(const float* __restrict__ x,
                                                  const float* __restrict__ mi,
                                                  const float* __restrict__ ss,
                                                  float* __restrict__ aout,
                                                  float* __restrict__ lam,
                                                  float* __restrict__ varPart,
                                                  int G3) {
  __shared__ float Xb[4096];
  int lane = threadIdx.x;
  float varacc = 0.f;

  for (int i = blockIdx.x; i < NB; i += G3) {
    __syncthreads();
    float w[ND];
    congruence1(x + (size_t)i * NN, mi, Xb, lane, w);
    float s2 = jacobi1s64(w, lane);
    float sig = sqrtf(fmaxf(s2, 1e-38f));
    float inv = 1.f / sig;
    lam[(size_t)i * ND + lane] = sig;
    float lg = logf(sig);
    varacc = fmaf(lg, lg, varacc);
    // park U^T
#pragma unroll
    for (int g2 = 0; g2 < 16; ++g2) {
      float4 u4 = make_float4(w[4 * g2 + 0] * inv, w[4 * g2 + 1] * inv,
                              w[4 * g2 + 2] * inv, w[4 * g2 + 3] * inv);
      *(float4*)(Xb + swz4(lane, g2)) = u4;
    }
    // Aout[r][lane] = sum_a ss[r][a] * U[a][lane]; U[a][lane] = Xb[row lane][a]
    float acc[ND];
#pragma unroll
    for (int r = 0; r < ND; ++r) acc[r] = 0.f;
    for (int a = 0; a < ND; ++a) {
      float ua = Xb[swzE(lane, a)];
      const float* ssr = ss + a * ND;
#pragma unroll
      for (int r = 0; r < ND; ++r) acc[r] = fmaf(ssr[r], ua, acc[r]);
    }
#pragma unroll
    for (int r = 0; r < ND; ++r)
      aout[(size_t)i * NN + r * ND + lane] = acc[r];
  }
  for (int o = 32; o; o >>= 1) varacc += __shfl_down(varacc, o);
  if (lane == 0) varPart[blockIdx.x] = varacc;
}

__global__ __launch_bounds__(64) void k_pfinal(const float* __restrict__ varPart,
                                               const float* __restrict__ scale,
                                               float* __restrict__ pout, int n) {
  int tid = threadIdx.x;
  float s = 0.f;
  for (int i = tid; i < n; i += 64) s += varPart[i];
  for (int o = 32; o; o >>= 1) s += __shfl_down(s, o);
  if (tid == 0) {
    float var = s * (1.f / (float)NB);
    float sd = sqrtf(var);
    pout[0] = scale[0] / (sd + 1e-5f);
  }
}

__global__ __launch_bounds__(256) void k_stage5(const float* __restrict__ ain,
                                                const float* __restrict__ lam,
                                                const float* __restrict__ pws,
                                                float* __restrict__ out) {
  __shared__ float Ab[ND][PAD];
  __shared__ float lp[ND];
  int tid = threadIdx.x;
  int i = blockIdx.x;
  for (int e = tid; e < NN; e += 256) Ab[e >> 6][e & 63] = ain[(size_t)i * NN + e];
  if (tid < ND) {
    float p = pws[0];
    lp[tid] = powf(lam[(size_t)i * ND + tid], p);
  }
  __syncthreads();
  int c = tid & 63, wq = tid >> 6;
  float acc[16];
#pragma unroll
  for (int k = 0; k < 16; ++k) acc[k] = 0.f;
  for (int j = 0; j < ND; ++j) {
    float m = lp[j] * Ab[c][j];
#pragma unroll
    for (int k = 0; k < 16; ++k) acc[k] = fmaf(Ab[wq + 4 * k][j], m, acc[k]);
  }
#pragma unroll
  for (int k = 0; k < 16; ++k)
    out[(size_t)i * NN + (wq + 4 * k) * ND + c] = acc[k];
}

// ---------------------------------------------------------------------------
extern "C" void kernel_launch(void* const* d_in, const int* in_sizes, int n_in,
                              void* d_out, int out_size, void* d_ws, size_t ws_size,
                              hipStream_t stream) {
  const float* x     = (const float*)d_in[0];
  const float* shift = (const float*)d_in[1];
  const float* scale = (const float*)d_in[2];
  float* out = (float*)d_out;
  float* ws  = (float*)d_ws;
  (void)in_sizes; (void)n_in; (void)out_size;

  size_t wsf = ws_size / 4;
  int G2 = G2_BLOCKS;
  if (OFF_TPART + (size_t)G2 * NN > wsf) {
    size_t avail = (wsf > OFF_TPART) ? (wsf - OFF_TPART) / NN : 1;
    if (avail < 1) avail = 1;
    if (avail < (size_t)G2) G2 = (int)avail;
  }

  k_mean_part<<<dim3(16, 32), 256, 0, stream>>>(x, ws + OFF_MEANPART);
  k_mean_final<<<16, 256, 0, stream>>>(ws + OFF_MEANPART, ws + OFF_MEANA);
  k_prep1<<<2, 256, 0, stream>>>(ws + OFF_MEANA, shift, ws + OFF_S, ws + OFF_SI,
                                 ws + OFF_SS);
  k_stage2<<<G2, 64, 0, stream>>>(x, ws + OFF_SI, ws + OFF_TPART, G2);
  k_reduce_t<<<16, 256, 0, stream>>>(ws + OFF_TPART, ws + OFF_TBAR, G2);
  k_prep2<<<1, 256, 0, stream>>>(ws + OFF_TBAR, ws + OFF_S, ws + OFF_MI);
  k_stage3<<<G3_BLOCKS, 64, 0, stream>>>(x, ws + OFF_MI, ws + OFF_SS, out,
                                         ws + OFF_LAM, ws + OFF_VARPART, G3_BLOCKS);
  k_pfinal<<<1, 64, 0, stream>>>(ws + OFF_VARPART, scale, ws + OFF_P, G3_BLOCKS);
  k_stage5<<<8192, 256, 0, stream>>>(out, ws + OFF_LAM, ws + OFF_P, out);
}